// Round 1
// baseline (414.132 us; speedup 1.0000x reference)
//
#include <hip/hip_runtime.h>

// CrossPatch: out[b,c,h,w] = x[b,c, src_h, src_w] + abs_pos[c*64 + n']
//   ph=h>>6, i=h&63, pw=w>>6, j=w&63, n=ph*8+pw, n'=(c+n)&63
//   src_h=(n'>>3)*64 + i, src_w=(n'&7)*64 + j
// B=4, C=64, H=W=512, PH=PW=8, PN=64, kh=kw=64. All pow2 -> shift/mask math.
// Memory-bound: 256 MB read + 256 MB write.

__global__ __launch_bounds__(256) void crosspatch_kernel(
    const float4* __restrict__ x4,
    const float*  __restrict__ abs_pos,
    float4*       __restrict__ out4)
{
    const int tid = blockIdx.x * blockDim.x + threadIdx.x;  // float4 index, 0..2^24-1

    // Decompose linear output float4 index: ((b*64 + c)*512 + h)*128 + wq
    const int wq = tid & 127;        // float4 column (w = wq*4), W/4 = 128
    const int t1 = tid >> 7;
    const int h  = t1 & 511;         // H = 512
    const int t2 = t1 >> 9;
    const int c  = t2 & 63;          // C = 64
    const int b  = t2 >> 6;

    const int w  = wq << 2;
    const int ph = h >> 6;           // kh = 64
    const int pw = w >> 6;           // kw = 64
    const int n  = (ph << 3) + pw;   // PW = 8
    const int np = (c + n) & 63;     // PN = 64

    const int src_h = ((np >> 3) << 6) | (h & 63);
    const int src_w = ((np & 7) << 6) | (w & 63);   // w&63 is mult of 4 -> aligned

    // float index = ((b*64+c) << 18) + (src_h << 9) + src_w ; divide by 4 for float4
    const int src4 = ((((b << 6) | c) << 18) + (src_h << 9) + src_w) >> 2;

    float4 v = x4[src4];
    const float bias = abs_pos[(c << 6) | np];
    v.x += bias; v.y += bias; v.z += bias; v.w += bias;
    out4[tid] = v;
}

extern "C" void kernel_launch(void* const* d_in, const int* in_sizes, int n_in,
                              void* d_out, int out_size, void* d_ws, size_t ws_size,
                              hipStream_t stream)
{
    const float4* x4      = (const float4*)d_in[0];
    const float*  abs_pos = (const float*)d_in[1];
    float4*       out4    = (float4*)d_out;

    // Total output floats = 4*64*512*512 = 2^26 ; float4 count = 2^24
    const int n_vec4 = (4 * 64 * 512 * 512) / 4;
    const int block  = 256;
    const int grid   = n_vec4 / block;  // 65536, exact

    crosspatch_kernel<<<grid, block, 0, stream>>>(x4, abs_pos, out4);
}